// Round 13
// baseline (382.216 us; speedup 1.0000x reference)
//
#include <hip/hip_runtime.h>
#include <hip/hip_fp16.h>
#include <math.h>

// ---------------------------------------------------------------------------
// DevignLite: 3-layer GCN + mean/max pool + MLP head.  N=100000, E=1.6M,
// D=64, G=256.
// Round 13:
//  - Aggregate: depth-2 gather pipeline (two 32B row gathers in flight per
//    lane-group; r12 had MLP=1 -> 2x latency gap vs VALU/HBM floors).
//  - k_cscan folded into k_chist via last-block ticket (12 dispatches).
// ---------------------------------------------------------------------------

#define BKT_LOG 9
#define BKT (1 << BKT_LOG)
#define CHUNK 4096

typedef _Float16 h2 __attribute__((ext_vector_type(2)));
typedef _Float16 f16x8 __attribute__((ext_vector_type(8)));
typedef float f32x4 __attribute__((ext_vector_type(4)));

union HU { unsigned u; h2 h; };
__device__ inline h2 h2bits(unsigned u) { HU x; x.u = u; return x.h; }

#if __has_builtin(__builtin_amdgcn_fdot2)
#define FDOT2(a, b, c) __builtin_amdgcn_fdot2((a), (b), (c), false)
#else
__device__ inline float FDOT2(h2 a, h2 b, float c) {
  return (float)a.x * (float)b.x + (float)a.y * (float)b.y + c;
}
#endif

#define MASK_X 0x00003C00u   // half2 (1,0)
#define MASK_Y 0x3C000000u   // half2 (0,1)

// acc[0..7] += convert of 8 halfs in v (via fdot2 with unit masks)
__device__ inline void acc8c(const uint4& v, float* acc) {
  const unsigned* w = (const unsigned*)&v;
#pragma unroll
  for (int k = 0; k < 4; k++) {
    h2 hv = h2bits(w[k]);
    acc[2 * k]     = FDOT2(hv, h2bits(MASK_X), acc[2 * k]);
    acc[2 * k + 1] = FDOT2(hv, h2bits(MASK_Y), acc[2 * k + 1]);
  }
}

// W conversion to fp16 B-frag layout (blocks 0-2) + workspace zeroing
// (block 3: chist+done, block 4: hsum/hmax/cntg).  Launched first.
__global__ __launch_bounds__(256) void k_wcvt(const float* __restrict__ W0,
                                              const float* __restrict__ W1,
                                              const float* __restrict__ W2,
                                              _Float16* __restrict__ Wf,
                                              int* __restrict__ chist,
                                              int* __restrict__ done,
                                              float* __restrict__ hz, int hzn) {
  if (blockIdx.x < 3) {
    const float* W = (blockIdx.x == 0) ? W0 : (blockIdx.x == 1) ? W1 : W2;
    _Float16* out = Wf + blockIdx.x * 4096;
    for (int i = threadIdx.x; i < 4096; i += 256) {
      int c = i >> 10, s = (i >> 9) & 1, l = (i >> 3) & 63, j = i & 7;
      int k = 32 * s + 8 * (l >> 4) + j;
      int ncol = 16 * c + (l & 15);
      out[i] = (_Float16)W[k * 64 + ncol];
    }
  } else if (blockIdx.x == 3) {
    chist[threadIdx.x] = 0;
    if (threadIdx.x == 0) *done = 0;
  } else {
    for (int i = threadIdx.x; i < hzn; i += 256) hz[i] = 0.f;
  }
}

// coarse histogram of dst >> BKT_LOG; last block also does the exclusive
// scan -> cbase[B+1] and cursor copy -> gcur (ticket pattern).
__global__ __launch_bounds__(256) void k_chist(const int* __restrict__ dst,
                                               int* __restrict__ chist,
                                               int* __restrict__ cbase,
                                               int* __restrict__ gcur,
                                               int* __restrict__ done,
                                               int E, int B) {
  __shared__ int h[256];
  __shared__ int last;
  h[threadIdx.x] = 0;
  __syncthreads();
  for (long e = (long)blockIdx.x * blockDim.x + threadIdx.x; e < E;
       e += (long)gridDim.x * blockDim.x)
    atomicAdd(&h[dst[e] >> BKT_LOG], 1);
  __syncthreads();
  if (threadIdx.x < B && h[threadIdx.x]) atomicAdd(&chist[threadIdx.x], h[threadIdx.x]);
  __threadfence();
  if (threadIdx.x == 0) last = (atomicAdd(done, 1) == (int)gridDim.x - 1);
  __syncthreads();
  if (!last) return;
  // ---- last block: exclusive scan of chist ----
  int v = (threadIdx.x < B) ? atomicAdd(&chist[threadIdx.x], 0) : 0;  // coherent
  h[threadIdx.x] = v;
  __syncthreads();
  for (int d = 1; d < 256; d <<= 1) {
    int t = (threadIdx.x >= (unsigned)d) ? h[threadIdx.x - d] : 0;
    __syncthreads();
    h[threadIdx.x] += t;
    __syncthreads();
  }
  if (threadIdx.x < B) {
    int ex = h[threadIdx.x] - v;
    cbase[threadIdx.x] = ex;
    gcur[threadIdx.x] = ex;
  }
  if (threadIdx.x == B) cbase[B] = E;
}

// partition: scatter packed (local_dst<<17 | src) into coarse-bucket order.
// LDS-staged: src/dst read exactly once from HBM.
__global__ __launch_bounds__(256) void k_part(const int* __restrict__ src,
                                              const int* __restrict__ dst,
                                              int* __restrict__ gcur,
                                              int* __restrict__ ebuf, int E, int B) {
  __shared__ int sA[CHUNK];
  __shared__ int dA[CHUNK];
  __shared__ int h[256], base[256];
  int tid = threadIdx.x;
  long c0 = (long)blockIdx.x * CHUNK;
  int m = (int)min((long)CHUNK, (long)E - c0);
  h[tid] = 0;
  __syncthreads();
  for (int i = tid; i < m; i += 256) {
    int s = src[c0 + i];
    int d = dst[c0 + i];
    sA[i] = s;
    dA[i] = d;
    atomicAdd(&h[d >> BKT_LOG], 1);
  }
  __syncthreads();
  if (tid < B && h[tid]) base[tid] = atomicAdd(&gcur[tid], h[tid]);
  __syncthreads();
  h[tid] = 0;   // reuse as per-bucket cursor
  __syncthreads();
  for (int i = tid; i < m; i += 256) {
    int s = sA[i], d = dA[i];
    int k = d >> BKT_LOG;
    int p = base[k] + atomicAdd(&h[k], 1);
    ebuf[p] = ((d & (BKT - 1)) << 17) | s;
  }
}

// per-bucket: node histogram + scan in LDS -> off/dinv, then place csrc.
__global__ __launch_bounds__(512) void k_bplace(const int* __restrict__ ebuf,
                                                const int* __restrict__ cbase,
                                                int* __restrict__ off,
                                                int* __restrict__ csrc,
                                                float* __restrict__ dinv,
                                                int N, int E) {
  __shared__ int s[512];
  __shared__ int cur[512];
  int b = blockIdx.x, tid = threadIdx.x;
  int n0 = b << BKT_LOG;
  int nn = min(BKT, N - n0);
  int e0 = cbase[b], e1 = cbase[b + 1];
  s[tid] = 0;
  __syncthreads();
  for (int e = e0 + tid; e < e1; e += 512) atomicAdd(&s[ebuf[e] >> 17], 1);
  __syncthreads();
  int deg = s[tid];
  for (int d = 1; d < 512; d <<= 1) {
    int t = (tid >= d) ? s[tid - d] : 0;
    __syncthreads();
    s[tid] += t;
    __syncthreads();
  }
  int excl = s[tid] - deg;
  if (tid < nn) {
    off[n0 + tid] = e0 + excl;
    dinv[n0 + tid] = 1.0f / sqrtf((float)(1 + deg));
  }
  cur[tid] = excl;
  __syncthreads();
  for (int e = e0 + tid; e < e1; e += 512) {
    int p = ebuf[e];
    int pos = e0 + atomicAdd(&cur[p >> 17], 1);
    csrc[pos] = p & 0x1FFFF;
  }
  if (b == 0 && tid == 0) off[N] = E;
}

// ---------------------------------------------------------------------------
// MFMA matmul: xh[c][node][16] = fp16( (in[node] @ W) * dinv[node]*scale )
// EMB: in = fp32 emb rows gathered by tok; else fp16 y in slab-major layout.
// ---------------------------------------------------------------------------
template <bool EMB>
__global__ __launch_bounds__(256) void k_mfmamm(const _Float16* __restrict__ y,
                                                const int* __restrict__ tok,
                                                const float* __restrict__ emb,
                                                const _Float16* __restrict__ Wf,
                                                const float* __restrict__ dinv,
                                                float scale,
                                                _Float16* __restrict__ xh,
                                                int n, int npad) {
  __shared__ _Float16 lds[4 * 16 * 72];
  int w = threadIdx.x >> 6, l = threadIdx.x & 63;
  int m = l & 15, q = l >> 4;
  int rbase = blockIdx.x * 64 + w * 16;

  f16x8 a0, a1;
  if (EMB) {
    int node = min(rbase + m, n - 1);
    const float* er = emb + (size_t)tok[node] * 64;
    float4 v0 = *(const float4*)(er + q * 8);
    float4 v1 = *(const float4*)(er + q * 8 + 4);
    float4 v2 = *(const float4*)(er + 32 + q * 8);
    float4 v3 = *(const float4*)(er + 32 + q * 8 + 4);
    a0[0] = (_Float16)v0.x; a0[1] = (_Float16)v0.y; a0[2] = (_Float16)v0.z; a0[3] = (_Float16)v0.w;
    a0[4] = (_Float16)v1.x; a0[5] = (_Float16)v1.y; a0[6] = (_Float16)v1.z; a0[7] = (_Float16)v1.w;
    a1[0] = (_Float16)v2.x; a1[1] = (_Float16)v2.y; a1[2] = (_Float16)v2.z; a1[3] = (_Float16)v2.w;
    a1[4] = (_Float16)v3.x; a1[5] = (_Float16)v3.y; a1[6] = (_Float16)v3.z; a1[7] = (_Float16)v3.w;
  } else {
    int node = rbase + m;
    a0 = *(const f16x8*)(y + ((size_t)(q >> 1) * npad + node) * 16 + (q & 1) * 8);
    a1 = *(const f16x8*)(y + ((size_t)((q >> 1) + 2) * npad + node) * 16 + (q & 1) * 8);
  }
  float4 d4 = *(const float4*)(dinv + rbase + q * 4);

  const f16x8* wf = (const f16x8*)Wf + l;
  f32x4 acc[4];
#pragma unroll
  for (int c = 0; c < 4; c++) {
    f32x4 z = {0.f, 0.f, 0.f, 0.f};
    z = __builtin_amdgcn_mfma_f32_16x16x32_f16(a0, wf[(c * 2 + 0) * 64], z, 0, 0, 0);
    z = __builtin_amdgcn_mfma_f32_16x16x32_f16(a1, wf[(c * 2 + 1) * 64], z, 0, 0, 0);
    acc[c] = z;
  }

  const float ds[4] = {d4.x * scale, d4.y * scale, d4.z * scale, d4.w * scale};
  _Float16* ldw = lds + w * 16 * 72;
#pragma unroll
  for (int c = 0; c < 4; c++)
#pragma unroll
    for (int r = 0; r < 4; r++)
      ldw[(q * 4 + r) * 72 + c * 16 + m] = (_Float16)(acc[c][r] * ds[r]);
  __syncthreads();

  int row2 = l & 15, c2 = l >> 4;
  int node = rbase + row2;
  if (node < n) {
    const uint4* s4 = (const uint4*)(ldw + row2 * 72 + c2 * 16);
    uint4 v0 = s4[0], v1 = s4[1];
    uint4* dst = (uint4*)(xh + ((size_t)c2 * npad + node) * 16);
    dst[0] = v0;
    dst[1] = v1;
  }
}

// ---------------------------------------------------------------------------
// Aggregate, slab-parallel, XCD-affine, depth-2 gather pipeline.
// chunk c = blockIdx&3; wave = 4 nodes; lane = (n4:bits4-5, g:bits1-3, o:bit0)
// out (slab-major [c][npad][16]) = fp16 4096*relu(conv + bias)
// conv = (dinv[t]/256) * (xh_c[t] + sum_in xh_c[s]).
// ---------------------------------------------------------------------------
__global__ __launch_bounds__(256) void k_aggregate(const int* __restrict__ off,
                                                   const int* __restrict__ csrc,
                                                   const float* __restrict__ dinv,
                                                   const _Float16* __restrict__ xh,
                                                   const float* __restrict__ bias,
                                                   _Float16* __restrict__ outp,
                                                   int n, int npad) {
  int c = blockIdx.x & 3;
  int lane = threadIdx.x & 63;
  int n4 = lane >> 4, g = (lane >> 1) & 7, o = lane & 1;
  int t = (blockIdx.x >> 2) * 16 + (threadIdx.x >> 6) * 4 + n4;
  bool valid = t < n;
  int tc = valid ? t : n - 1;
  int e0 = off[tc], e1 = off[tc + 1];
  if (!valid) e1 = e0;
  const uint4* x4 = (const uint4*)xh + (size_t)c * npad * 2;   // 32B rows

  float acc[8];
#pragma unroll
  for (int k = 0; k < 8; k++) acc[k] = 0.f;
  if (g == 0) acc8c(x4[(size_t)tc * 2 + o], acc);   // self term

  // depth-2 software pipeline: edges iA and iA+8 gathered concurrently,
  // next pair of indices loaded before the gather waits.
  int iA = e0 + g;
  bool aA = iA < e1, aB = iA + 8 < e1;
  int sA = aA ? csrc[iA] : 0;
  int sB = aB ? csrc[iA + 8] : 0;
  while (aA) {
    uint4 vA = x4[(size_t)sA * 2 + o];       // gather 1 (in flight)
    uint4 vB;
    if (aB) vB = x4[(size_t)sB * 2 + o];     // gather 2 (in flight)
    int iN = iA + 16;
    bool aN = iN < e1, aM = iN + 8 < e1;
    int sN = 0, sM = 0;
    if (aN) sN = csrc[iN];                   // next indices (in flight)
    if (aM) sM = csrc[iN + 8];
    acc8c(vA, acc);
    if (aB) acc8c(vB, acc);
    iA = iN; aA = aN; sA = sN;
    aB = aM; sB = sM;
  }

  // reduce over g (lane bits 1-3)
#pragma unroll
  for (int mm = 2; mm <= 8; mm <<= 1) {
#pragma unroll
    for (int k = 0; k < 8; k++) acc[k] += __shfl_xor(acc[k], mm);
  }

  if (valid && g == 0) {
    float sc = dinv[t] * (1.0f / 256.0f);
    int f0 = c * 16 + o * 8;
    float4 bb0 = *(const float4*)(bias + f0);
    float4 bb1 = *(const float4*)(bias + f0 + 4);
    const float bs[8] = {bb0.x, bb0.y, bb0.z, bb0.w, bb1.x, bb1.y, bb1.z, bb1.w};
    _Float16 hh[8];
#pragma unroll
    for (int k = 0; k < 8; k++)
      hh[k] = (_Float16)(fmaxf(acc[k] * sc + bs[k], 0.f) * 4096.f);
    *(uint4*)(outp + ((size_t)c * npad + t) * 16 + o * 8) = *(const uint4*)hh;
  }
}

// batch is sorted: per-wave register segment reduction over slab-major fp16 y.
__global__ __launch_bounds__(256) void k_pool(const _Float16* __restrict__ x,
                                              const int* __restrict__ batch,
                                              float* __restrict__ hsum,
                                              float* __restrict__ hmax,
                                              int* __restrict__ cntg,
                                              int n, int npad) {
  int wid = (blockIdx.x * blockDim.x + threadIdx.x) >> 6;
  int lane = threadIdx.x & 63;
  int i0 = wid * 64;
  if (i0 >= n) return;
  int i1 = min(i0 + 64, n);
  size_t sb = (size_t)(lane >> 4) * npad * 16 + (lane & 15);
  int batch_l = (i0 + lane < n) ? batch[i0 + lane] : 0;
  float gsum = 0.f, gmax = 0.f;
  int cur = __shfl(batch_l, 0);
  int c = 0;
  for (int i = i0; i < i1; i++) {
    int g = __shfl(batch_l, i - i0);
    if (g != cur) {
      atomicAdd(&hsum[cur * 64 + lane], gsum);
      atomicMax((int*)&hmax[cur * 64 + lane], __float_as_int(gmax));
      if (lane == 0) atomicAdd(&cntg[cur], c);
      gsum = 0.f; gmax = 0.f; c = 0; cur = g;
    }
    float v = (float)x[sb + (size_t)i * 16];   // relu+bias already folded
    gsum += v;
    gmax = fmaxf(gmax, v);
    c++;
  }
  atomicAdd(&hsum[cur * 64 + lane], gsum);
  atomicMax((int*)&hmax[cur * 64 + lane], __float_as_int(gmax));
  if (lane == 0) atomicAdd(&cntg[cur], c);
}

// one block (64 threads) per graph: logits = relu(h@Wc1+bc1)@Wc2+bc2
__global__ __launch_bounds__(64) void k_cls(const float* __restrict__ hsum,
                                            const float* __restrict__ hmax,
                                            const int* __restrict__ cnt,
                                            const float* __restrict__ Wc1,
                                            const float* __restrict__ bc1,
                                            const float* __restrict__ Wc2,
                                            const float* __restrict__ bc2,
                                            float* __restrict__ out) {
  __shared__ float h[128];
  __shared__ float hid[64];
  int g = blockIdx.x, j = threadIdx.x;
  int c = cnt[g];
  float cf = (float)(c > 0 ? c : 1);
  h[j] = hsum[g * 64 + j] / cf * (1.0f / 4096.0f);
  h[64 + j] = hmax[g * 64 + j] * (1.0f / 4096.0f);
  __syncthreads();
  float acc = bc1[j];
  for (int k = 0; k < 128; k++) acc += h[k] * Wc1[k * 64 + j];
  hid[j] = fmaxf(acc, 0.f);
  __syncthreads();
  if (j < 2) {
    float a = bc2[j];
    for (int k = 0; k < 64; k++) a += hid[k] * Wc2[k * 2 + j];
    out[g * 2 + j] = a;
  }
}

extern "C" void kernel_launch(void* const* d_in, const int* in_sizes, int n_in,
                              void* d_out, int out_size, void* d_ws, size_t ws_size,
                              hipStream_t stream) {
  const int N = in_sizes[0];
  const int E = in_sizes[1] / 2;
  const int G = out_size / 2;
  const int B = (N + BKT - 1) >> BKT_LOG;
  const int Npad = (N + 63) & ~63;

  const int* tok   = (const int*)d_in[0];
  const int* ei    = (const int*)d_in[1];
  const int* batch = (const int*)d_in[2];
  const float* emb = (const float*)d_in[3];
  const float* W0 = (const float*)d_in[4];  const float* b0 = (const float*)d_in[5];
  const float* W1 = (const float*)d_in[6];  const float* b1 = (const float*)d_in[7];
  const float* W2 = (const float*)d_in[8];  const float* b2 = (const float*)d_in[9];
  const float* Wc1 = (const float*)d_in[10]; const float* bc1 = (const float*)d_in[11];
  const float* Wc2 = (const float*)d_in[12]; const float* bc2 = (const float*)d_in[13];
  const int* srcp = ei;
  const int* dstp = ei + E;

  // ---- workspace carve-up (4-byte units) ----
  int* off    = (int*)d_ws;                      // N+2
  int* csrc   = off + N + 2;                     // E
  float* dinv = (float*)(csrc + E);              // Npad
  int* chist  = (int*)(dinv + Npad);             // 256
  int* cbase  = chist + 256;                     // 256 (B+1 used)
  int* gcur   = cbase + 256;                     // 256
  int* done   = gcur + 256;                      // 1 (+pad)
  _Float16* Wf = (_Float16*)(done + 2);          // 3*4096 halfs
  _Float16* xh = Wf + 3 * 4096;                  // 4 slabs x Npad x 16 halfs
  _Float16* y  = xh + (size_t)Npad * 64;         // 4 slabs x Npad x 16 halfs
  int* ebuf   = (int*)(y + (size_t)Npad * 64);   // E ints (dead after bplace)
  float* hsum = (float*)(ebuf + E);              // G*64
  float* hmax = hsum + (size_t)G * 64;           // G*64
  int*   cntg = (int*)(hmax + (size_t)G * 64);   // G

  auto cdiv = [](long a, long b) { return (int)((a + b - 1) / b); };
  const int aggBlocks = 4 * cdiv(N, 16);   // blockIdx&3 = slab -> XCD affine

  // ---- weight conversion + workspace zeroing ----
  k_wcvt<<<5, 256, 0, stream>>>(W0, W1, W2, Wf, chist, done, hsum, G * 129);

  // ---- CSR build (chist+scan fused via last-block ticket) ----
  k_chist<<<cdiv(E, CHUNK), 256, 0, stream>>>(dstp, chist, cbase, gcur, done, E, B);
  k_part<<<cdiv(E, CHUNK), 256, 0, stream>>>(srcp, dstp, gcur, ebuf, E, B);
  k_bplace<<<B, 512, 0, stream>>>(ebuf, cbase, off, csrc, dinv, N, E);

  // ---- 3 GCN layers ----
  k_mfmamm<true><<<cdiv(N, 64), 256, 0, stream>>>(nullptr, tok, emb, Wf, dinv, 256.f, xh, N, Npad);
  k_aggregate<<<aggBlocks, 256, 0, stream>>>(off, csrc, dinv, xh, b0, y, N, Npad);

  k_mfmamm<false><<<cdiv(N, 64), 256, 0, stream>>>(y, nullptr, nullptr, Wf + 4096, dinv, 1.f / 16.f, xh, N, Npad);
  k_aggregate<<<aggBlocks, 256, 0, stream>>>(off, csrc, dinv, xh, b1, y, N, Npad);

  k_mfmamm<false><<<cdiv(N, 64), 256, 0, stream>>>(y, nullptr, nullptr, Wf + 8192, dinv, 1.f / 16.f, xh, N, Npad);
  k_aggregate<<<aggBlocks, 256, 0, stream>>>(off, csrc, dinv, xh, b2, y, N, Npad);

  // ---- pooling ----
  k_pool<<<cdiv(N, 256), 256, 0, stream>>>(y, batch, hsum, hmax, cntg, N, Npad);

  // ---- classifier head ----
  k_cls<<<G, 64, 0, stream>>>(hsum, hmax, cntg, Wc1, bc1, Wc2, bc2, (float*)d_out);
}

// Round 14
// 367.631 us; speedup vs baseline: 1.0397x; 1.0397x over previous
//
#include <hip/hip_runtime.h>
#include <hip/hip_fp16.h>
#include <math.h>

// ---------------------------------------------------------------------------
// DevignLite: 3-layer GCN + mean/max pool + MLP head.  N=100000, E=1.6M,
// D=64, G=256.
// Round 14:
//  - REVERT r13's chist/cscan ticket fusion (391 device fences + serializing
//    atomics cost ~+16us).  Separate kernels as in r12.  Depth-2 aggregate
//    pipeline kept (proven 54.5->52.3us).
//  - Pooling fused into 3rd aggregate (POOL): LDS 16x17 tile + 16 leader
//    threads do sorted-batch segmented reduce -> ~1 atomic per
//    (segment x feat); agg3 writes NO y (saves 12.8MB W + 12.8MB R + launch).
// ---------------------------------------------------------------------------

#define BKT_LOG 9
#define BKT (1 << BKT_LOG)
#define CHUNK 4096

typedef _Float16 h2 __attribute__((ext_vector_type(2)));
typedef _Float16 f16x8 __attribute__((ext_vector_type(8)));
typedef float f32x4 __attribute__((ext_vector_type(4)));

union HU { unsigned u; h2 h; };
__device__ inline h2 h2bits(unsigned u) { HU x; x.u = u; return x.h; }

#if __has_builtin(__builtin_amdgcn_fdot2)
#define FDOT2(a, b, c) __builtin_amdgcn_fdot2((a), (b), (c), false)
#else
__device__ inline float FDOT2(h2 a, h2 b, float c) {
  return (float)a.x * (float)b.x + (float)a.y * (float)b.y + c;
}
#endif

#define MASK_X 0x00003C00u   // half2 (1,0)
#define MASK_Y 0x3C000000u   // half2 (0,1)

// acc[0..7] += convert of 8 halfs in v (via fdot2 with unit masks)
__device__ inline void acc8c(const uint4& v, float* acc) {
  const unsigned* w = (const unsigned*)&v;
#pragma unroll
  for (int k = 0; k < 4; k++) {
    h2 hv = h2bits(w[k]);
    acc[2 * k]     = FDOT2(hv, h2bits(MASK_X), acc[2 * k]);
    acc[2 * k + 1] = FDOT2(hv, h2bits(MASK_Y), acc[2 * k + 1]);
  }
}

// W conversion to fp16 B-frag layout (blocks 0-2) + workspace zeroing
// (block 3: chist, block 4: hsum/hmax/cntg).  Launched first.
__global__ __launch_bounds__(256) void k_wcvt(const float* __restrict__ W0,
                                              const float* __restrict__ W1,
                                              const float* __restrict__ W2,
                                              _Float16* __restrict__ Wf,
                                              int* __restrict__ chist,
                                              float* __restrict__ hz, int hzn) {
  if (blockIdx.x < 3) {
    const float* W = (blockIdx.x == 0) ? W0 : (blockIdx.x == 1) ? W1 : W2;
    _Float16* out = Wf + blockIdx.x * 4096;
    for (int i = threadIdx.x; i < 4096; i += 256) {
      int c = i >> 10, s = (i >> 9) & 1, l = (i >> 3) & 63, j = i & 7;
      int k = 32 * s + 8 * (l >> 4) + j;
      int ncol = 16 * c + (l & 15);
      out[i] = (_Float16)W[k * 64 + ncol];
    }
  } else if (blockIdx.x == 3) {
    chist[threadIdx.x] = 0;
  } else {
    for (int i = threadIdx.x; i < hzn; i += 256) hz[i] = 0.f;
  }
}

// coarse histogram of dst >> BKT_LOG
__global__ __launch_bounds__(256) void k_chist(const int* __restrict__ dst,
                                               int* __restrict__ chist, int E, int B) {
  __shared__ int h[256];
  h[threadIdx.x] = 0;
  __syncthreads();
  for (long e = (long)blockIdx.x * blockDim.x + threadIdx.x; e < E;
       e += (long)gridDim.x * blockDim.x)
    atomicAdd(&h[dst[e] >> BKT_LOG], 1);
  __syncthreads();
  if (threadIdx.x < B && h[threadIdx.x]) atomicAdd(&chist[threadIdx.x], h[threadIdx.x]);
}

// exclusive scan of chist[B] -> cbase[B+1]; cursor copy -> gcur
__global__ __launch_bounds__(256) void k_cscan(const int* __restrict__ chist,
                                               int* __restrict__ cbase,
                                               int* __restrict__ gcur, int E, int B) {
  __shared__ int s[256];
  int v = (threadIdx.x < B) ? chist[threadIdx.x] : 0;
  s[threadIdx.x] = v;
  __syncthreads();
  for (int d = 1; d < 256; d <<= 1) {
    int t = (threadIdx.x >= (unsigned)d) ? s[threadIdx.x - d] : 0;
    __syncthreads();
    s[threadIdx.x] += t;
    __syncthreads();
  }
  if (threadIdx.x < B) {
    int ex = s[threadIdx.x] - v;
    cbase[threadIdx.x] = ex;
    gcur[threadIdx.x] = ex;
  }
  if (threadIdx.x == B) cbase[B] = E;
}

// partition: scatter packed (local_dst<<17 | src) into coarse-bucket order.
// LDS-staged: src/dst read exactly once from HBM.
__global__ __launch_bounds__(256) void k_part(const int* __restrict__ src,
                                              const int* __restrict__ dst,
                                              int* __restrict__ gcur,
                                              int* __restrict__ ebuf, int E, int B) {
  __shared__ int sA[CHUNK];
  __shared__ int dA[CHUNK];
  __shared__ int h[256], base[256];
  int tid = threadIdx.x;
  long c0 = (long)blockIdx.x * CHUNK;
  int m = (int)min((long)CHUNK, (long)E - c0);
  h[tid] = 0;
  __syncthreads();
  for (int i = tid; i < m; i += 256) {
    int s = src[c0 + i];
    int d = dst[c0 + i];
    sA[i] = s;
    dA[i] = d;
    atomicAdd(&h[d >> BKT_LOG], 1);
  }
  __syncthreads();
  if (tid < B && h[tid]) base[tid] = atomicAdd(&gcur[tid], h[tid]);
  __syncthreads();
  h[tid] = 0;   // reuse as per-bucket cursor
  __syncthreads();
  for (int i = tid; i < m; i += 256) {
    int s = sA[i], d = dA[i];
    int k = d >> BKT_LOG;
    int p = base[k] + atomicAdd(&h[k], 1);
    ebuf[p] = ((d & (BKT - 1)) << 17) | s;
  }
}

// per-bucket: node histogram + scan in LDS -> off/dinv, then place csrc.
__global__ __launch_bounds__(512) void k_bplace(const int* __restrict__ ebuf,
                                                const int* __restrict__ cbase,
                                                int* __restrict__ off,
                                                int* __restrict__ csrc,
                                                float* __restrict__ dinv,
                                                int N, int E) {
  __shared__ int s[512];
  __shared__ int cur[512];
  int b = blockIdx.x, tid = threadIdx.x;
  int n0 = b << BKT_LOG;
  int nn = min(BKT, N - n0);
  int e0 = cbase[b], e1 = cbase[b + 1];
  s[tid] = 0;
  __syncthreads();
  for (int e = e0 + tid; e < e1; e += 512) atomicAdd(&s[ebuf[e] >> 17], 1);
  __syncthreads();
  int deg = s[tid];
  for (int d = 1; d < 512; d <<= 1) {
    int t = (tid >= d) ? s[tid - d] : 0;
    __syncthreads();
    s[tid] += t;
    __syncthreads();
  }
  int excl = s[tid] - deg;
  if (tid < nn) {
    off[n0 + tid] = e0 + excl;
    dinv[n0 + tid] = 1.0f / sqrtf((float)(1 + deg));
  }
  cur[tid] = excl;
  __syncthreads();
  for (int e = e0 + tid; e < e1; e += 512) {
    int p = ebuf[e];
    int pos = e0 + atomicAdd(&cur[p >> 17], 1);
    csrc[pos] = p & 0x1FFFF;
  }
  if (b == 0 && tid == 0) off[N] = E;
}

// ---------------------------------------------------------------------------
// MFMA matmul: xh[c][node][16] = fp16( (in[node] @ W) * dinv[node]*scale )
// EMB: in = fp32 emb rows gathered by tok; else fp16 y in slab-major layout.
// ---------------------------------------------------------------------------
template <bool EMB>
__global__ __launch_bounds__(256) void k_mfmamm(const _Float16* __restrict__ y,
                                                const int* __restrict__ tok,
                                                const float* __restrict__ emb,
                                                const _Float16* __restrict__ Wf,
                                                const float* __restrict__ dinv,
                                                float scale,
                                                _Float16* __restrict__ xh,
                                                int n, int npad) {
  __shared__ _Float16 lds[4 * 16 * 72];
  int w = threadIdx.x >> 6, l = threadIdx.x & 63;
  int m = l & 15, q = l >> 4;
  int rbase = blockIdx.x * 64 + w * 16;

  f16x8 a0, a1;
  if (EMB) {
    int node = min(rbase + m, n - 1);
    const float* er = emb + (size_t)tok[node] * 64;
    float4 v0 = *(const float4*)(er + q * 8);
    float4 v1 = *(const float4*)(er + q * 8 + 4);
    float4 v2 = *(const float4*)(er + 32 + q * 8);
    float4 v3 = *(const float4*)(er + 32 + q * 8 + 4);
    a0[0] = (_Float16)v0.x; a0[1] = (_Float16)v0.y; a0[2] = (_Float16)v0.z; a0[3] = (_Float16)v0.w;
    a0[4] = (_Float16)v1.x; a0[5] = (_Float16)v1.y; a0[6] = (_Float16)v1.z; a0[7] = (_Float16)v1.w;
    a1[0] = (_Float16)v2.x; a1[1] = (_Float16)v2.y; a1[2] = (_Float16)v2.z; a1[3] = (_Float16)v2.w;
    a1[4] = (_Float16)v3.x; a1[5] = (_Float16)v3.y; a1[6] = (_Float16)v3.z; a1[7] = (_Float16)v3.w;
  } else {
    int node = rbase + m;
    a0 = *(const f16x8*)(y + ((size_t)(q >> 1) * npad + node) * 16 + (q & 1) * 8);
    a1 = *(const f16x8*)(y + ((size_t)((q >> 1) + 2) * npad + node) * 16 + (q & 1) * 8);
  }
  float4 d4 = *(const float4*)(dinv + rbase + q * 4);

  const f16x8* wf = (const f16x8*)Wf + l;
  f32x4 acc[4];
#pragma unroll
  for (int c = 0; c < 4; c++) {
    f32x4 z = {0.f, 0.f, 0.f, 0.f};
    z = __builtin_amdgcn_mfma_f32_16x16x32_f16(a0, wf[(c * 2 + 0) * 64], z, 0, 0, 0);
    z = __builtin_amdgcn_mfma_f32_16x16x32_f16(a1, wf[(c * 2 + 1) * 64], z, 0, 0, 0);
    acc[c] = z;
  }

  const float ds[4] = {d4.x * scale, d4.y * scale, d4.z * scale, d4.w * scale};
  _Float16* ldw = lds + w * 16 * 72;
#pragma unroll
  for (int c = 0; c < 4; c++)
#pragma unroll
    for (int r = 0; r < 4; r++)
      ldw[(q * 4 + r) * 72 + c * 16 + m] = (_Float16)(acc[c][r] * ds[r]);
  __syncthreads();

  int row2 = l & 15, c2 = l >> 4;
  int node = rbase + row2;
  if (node < n) {
    const uint4* s4 = (const uint4*)(ldw + row2 * 72 + c2 * 16);
    uint4 v0 = s4[0], v1 = s4[1];
    uint4* dst = (uint4*)(xh + ((size_t)c2 * npad + node) * 16);
    dst[0] = v0;
    dst[1] = v1;
  }
}

// ---------------------------------------------------------------------------
// Aggregate, slab-parallel, XCD-affine, depth-2 gather pipeline.
// chunk c = blockIdx&3; wave = 4 nodes; lane = (n4:bits4-5, g:bits1-3, o:bit0)
// !POOL: out (slab-major [c][npad][16]) = fp16 4096*relu(conv + bias)
// POOL:  no y output; fp32 post-relu vals -> LDS -> segmented (sorted batch)
//        reduce -> hsum/hmax/cntg atomics (one per segment x feat).
// conv = (dinv[t]/256) * (xh_c[t] + sum_in xh_c[s]).
// ---------------------------------------------------------------------------
template <bool POOL>
__global__ __launch_bounds__(256) void k_aggregate(const int* __restrict__ off,
                                                   const int* __restrict__ csrc,
                                                   const float* __restrict__ dinv,
                                                   const _Float16* __restrict__ xh,
                                                   const float* __restrict__ bias,
                                                   _Float16* __restrict__ outp,
                                                   const int* __restrict__ batch,
                                                   float* __restrict__ hsum,
                                                   float* __restrict__ hmax,
                                                   int* __restrict__ cntg,
                                                   int n, int npad) {
  __shared__ float sm[16][17];
  __shared__ int sb[16];
  int c = blockIdx.x & 3;
  int lane = threadIdx.x & 63;
  int n4 = lane >> 4, g = (lane >> 1) & 7, o = lane & 1;
  int tbase = (blockIdx.x >> 2) * 16;
  int t = tbase + (threadIdx.x >> 6) * 4 + n4;
  bool valid = t < n;
  int tc = valid ? t : n - 1;
  int e0 = off[tc], e1 = off[tc + 1];
  if (!valid) e1 = e0;
  const uint4* x4 = (const uint4*)xh + (size_t)c * npad * 2;   // 32B rows

  float acc[8];
#pragma unroll
  for (int k = 0; k < 8; k++) acc[k] = 0.f;
  if (g == 0) acc8c(x4[(size_t)tc * 2 + o], acc);   // self term

  // depth-2 software pipeline: edges iA and iA+8 gathered concurrently.
  int iA = e0 + g;
  bool aA = iA < e1, aB = iA + 8 < e1;
  int sA = aA ? csrc[iA] : 0;
  int sB = aB ? csrc[iA + 8] : 0;
  while (aA) {
    uint4 vA = x4[(size_t)sA * 2 + o];
    uint4 vB;
    if (aB) vB = x4[(size_t)sB * 2 + o];
    int iN = iA + 16;
    bool aN = iN < e1, aM = iN + 8 < e1;
    int sN = 0, sM = 0;
    if (aN) sN = csrc[iN];
    if (aM) sM = csrc[iN + 8];
    acc8c(vA, acc);
    if (aB) acc8c(vB, acc);
    iA = iN; aA = aN; sA = sN;
    aB = aM; sB = sM;
  }

  // reduce over g (lane bits 1-3)
#pragma unroll
  for (int mm = 2; mm <= 8; mm <<= 1) {
#pragma unroll
    for (int k = 0; k < 8; k++) acc[k] += __shfl_xor(acc[k], mm);
  }

  if (POOL) {
    // fp32 post-relu values into LDS tile [node-in-block][feat-in-slab]
    int ni = (threadIdx.x >> 6) * 4 + n4;
    if (valid && g == 0) {
      float sc = dinv[t] * (1.0f / 256.0f);
      int f0 = c * 16 + o * 8;
      float4 bb0 = *(const float4*)(bias + f0);
      float4 bb1 = *(const float4*)(bias + f0 + 4);
      const float bs[8] = {bb0.x, bb0.y, bb0.z, bb0.w, bb1.x, bb1.y, bb1.z, bb1.w};
#pragma unroll
      for (int k = 0; k < 8; k++)
        sm[ni][o * 8 + k] = fmaxf(acc[k] * sc + bs[k], 0.f);
    }
    if (threadIdx.x < 16) {
      int tt = tbase + threadIdx.x;
      sb[threadIdx.x] = (tt < n) ? batch[tt] : -1;
    }
    __syncthreads();
    if (threadIdx.x < 16) {
      int f = threadIdx.x;          // feature within slab
      int fg = c * 16 + f;          // global feature
      float rs = 0.f, rm = 0.f;
      int curb = sb[0], run = 0;
      for (int i = 0; i < 16; i++) {
        int bi = sb[i];
        if (bi < 0) break;
        if (bi != curb) {
          atomicAdd(&hsum[curb * 64 + fg], rs);
          atomicMax((int*)&hmax[curb * 64 + fg], __float_as_int(rm));
          if (f == 0 && c == 0) atomicAdd(&cntg[curb], run);
          rs = 0.f; rm = 0.f; run = 0; curb = bi;
        }
        float v = sm[i][f];
        rs += v;
        rm = fmaxf(rm, v);
        run++;
      }
      if (run > 0 && curb >= 0) {
        atomicAdd(&hsum[curb * 64 + fg], rs);
        atomicMax((int*)&hmax[curb * 64 + fg], __float_as_int(rm));
        if (f == 0 && c == 0) atomicAdd(&cntg[curb], run);
      }
    }
  } else {
    if (valid && g == 0) {
      float sc = dinv[t] * (1.0f / 256.0f);
      int f0 = c * 16 + o * 8;
      float4 bb0 = *(const float4*)(bias + f0);
      float4 bb1 = *(const float4*)(bias + f0 + 4);
      const float bs[8] = {bb0.x, bb0.y, bb0.z, bb0.w, bb1.x, bb1.y, bb1.z, bb1.w};
      _Float16 hh[8];
#pragma unroll
      for (int k = 0; k < 8; k++)
        hh[k] = (_Float16)(fmaxf(acc[k] * sc + bs[k], 0.f) * 4096.f);
      *(uint4*)(outp + ((size_t)c * npad + t) * 16 + o * 8) = *(const uint4*)hh;
    }
  }
}

// one block (64 threads) per graph: logits = relu(h@Wc1+bc1)@Wc2+bc2
// hsum/hmax are UNSCALED fp32 (pool fused in aggregate).
__global__ __launch_bounds__(64) void k_cls(const float* __restrict__ hsum,
                                            const float* __restrict__ hmax,
                                            const int* __restrict__ cnt,
                                            const float* __restrict__ Wc1,
                                            const float* __restrict__ bc1,
                                            const float* __restrict__ Wc2,
                                            const float* __restrict__ bc2,
                                            float* __restrict__ out) {
  __shared__ float h[128];
  __shared__ float hid[64];
  int g = blockIdx.x, j = threadIdx.x;
  int c = cnt[g];
  float cf = (float)(c > 0 ? c : 1);
  h[j] = hsum[g * 64 + j] / cf;
  h[64 + j] = hmax[g * 64 + j];
  __syncthreads();
  float acc = bc1[j];
  for (int k = 0; k < 128; k++) acc += h[k] * Wc1[k * 64 + j];
  hid[j] = fmaxf(acc, 0.f);
  __syncthreads();
  if (j < 2) {
    float a = bc2[j];
    for (int k = 0; k < 64; k++) a += hid[k] * Wc2[k * 2 + j];
    out[g * 2 + j] = a;
  }
}

extern "C" void kernel_launch(void* const* d_in, const int* in_sizes, int n_in,
                              void* d_out, int out_size, void* d_ws, size_t ws_size,
                              hipStream_t stream) {
  const int N = in_sizes[0];
  const int E = in_sizes[1] / 2;
  const int G = out_size / 2;
  const int B = (N + BKT - 1) >> BKT_LOG;
  const int Npad = (N + 63) & ~63;

  const int* tok   = (const int*)d_in[0];
  const int* ei    = (const int*)d_in[1];
  const int* batch = (const int*)d_in[2];
  const float* emb = (const float*)d_in[3];
  const float* W0 = (const float*)d_in[4];  const float* b0 = (const float*)d_in[5];
  const float* W1 = (const float*)d_in[6];  const float* b1 = (const float*)d_in[7];
  const float* W2 = (const float*)d_in[8];  const float* b2 = (const float*)d_in[9];
  const float* Wc1 = (const float*)d_in[10]; const float* bc1 = (const float*)d_in[11];
  const float* Wc2 = (const float*)d_in[12]; const float* bc2 = (const float*)d_in[13];
  const int* srcp = ei;
  const int* dstp = ei + E;

  // ---- workspace carve-up (4-byte units) ----
  int* off    = (int*)d_ws;                      // N+2
  int* csrc   = off + N + 2;                     // E
  float* dinv = (float*)(csrc + E);              // Npad
  int* chist  = (int*)(dinv + Npad);             // 256
  int* cbase  = chist + 256;                     // 256 (B+1 used)
  int* gcur   = cbase + 256;                     // 256
  _Float16* Wf = (_Float16*)(gcur + 256);        // 3*4096 halfs
  _Float16* xh = Wf + 3 * 4096;                  // 4 slabs x Npad x 16 halfs
  _Float16* y  = xh + (size_t)Npad * 64;         // 4 slabs x Npad x 16 halfs
  int* ebuf   = (int*)(y + (size_t)Npad * 64);   // E ints (dead after bplace)
  float* hsum = (float*)(ebuf + E);              // G*64
  float* hmax = hsum + (size_t)G * 64;           // G*64
  int*   cntg = (int*)(hmax + (size_t)G * 64);   // G

  auto cdiv = [](long a, long b) { return (int)((a + b - 1) / b); };
  const int aggBlocks = 4 * cdiv(N, 16);   // blockIdx&3 = slab -> XCD affine

  // ---- weight conversion + workspace zeroing ----
  k_wcvt<<<5, 256, 0, stream>>>(W0, W1, W2, Wf, chist, hsum, G * 129);

  // ---- CSR build ----
  k_chist<<<cdiv(E, CHUNK), 256, 0, stream>>>(dstp, chist, E, B);
  k_cscan<<<1, 256, 0, stream>>>(chist, cbase, gcur, E, B);
  k_part<<<cdiv(E, CHUNK), 256, 0, stream>>>(srcp, dstp, gcur, ebuf, E, B);
  k_bplace<<<B, 512, 0, stream>>>(ebuf, cbase, off, csrc, dinv, N, E);

  // ---- 3 GCN layers (pool fused into layer-3 aggregate) ----
  k_mfmamm<true><<<cdiv(N, 64), 256, 0, stream>>>(nullptr, tok, emb, Wf, dinv, 256.f, xh, N, Npad);
  k_aggregate<false><<<aggBlocks, 256, 0, stream>>>(off, csrc, dinv, xh, b0, y,
                                                    nullptr, nullptr, nullptr, nullptr, N, Npad);

  k_mfmamm<false><<<cdiv(N, 64), 256, 0, stream>>>(y, nullptr, nullptr, Wf + 4096, dinv, 1.f / 16.f, xh, N, Npad);
  k_aggregate<false><<<aggBlocks, 256, 0, stream>>>(off, csrc, dinv, xh, b1, y,
                                                    nullptr, nullptr, nullptr, nullptr, N, Npad);

  k_mfmamm<false><<<cdiv(N, 64), 256, 0, stream>>>(y, nullptr, nullptr, Wf + 8192, dinv, 1.f / 16.f, xh, N, Npad);
  k_aggregate<true><<<aggBlocks, 256, 0, stream>>>(off, csrc, dinv, xh, b2, nullptr,
                                                   batch, hsum, hmax, cntg, N, Npad);

  // ---- classifier head ----
  k_cls<<<G, 64, 0, stream>>>(hsum, hmax, cntg, Wc1, bc1, Wc2, bc2, (float*)d_out);
}

// Round 15
// 366.046 us; speedup vs baseline: 1.0442x; 1.0043x over previous
//
#include <hip/hip_runtime.h>
#include <hip/hip_fp16.h>
#include <math.h>

// ---------------------------------------------------------------------------
// DevignLite: 3-layer GCN + mean/max pool + MLP head.  N=100000, E=1.6M,
// D=64, G=256.
// Round 15: REVERT r14's pool-into-aggregate fusion (barrier coupled the 4
// waves -> block time = max wave time; agg3 52->76us).  Separate k_pool
// (~9us, r12-proven).  Keep: depth-2 gather pipeline, slab-major y, MFMA
// matmul, single-writer CSR build, wcvt-fused zeroing.
// Ledger: r12=372 (agg 54.5x3), r13 ticket-fusion +16 REVERTED, r14 pool
// fusion +24 on agg3 REVERTED here.
// ---------------------------------------------------------------------------

#define BKT_LOG 9
#define BKT (1 << BKT_LOG)
#define CHUNK 4096

typedef _Float16 h2 __attribute__((ext_vector_type(2)));
typedef _Float16 f16x8 __attribute__((ext_vector_type(8)));
typedef float f32x4 __attribute__((ext_vector_type(4)));

union HU { unsigned u; h2 h; };
__device__ inline h2 h2bits(unsigned u) { HU x; x.u = u; return x.h; }

#if __has_builtin(__builtin_amdgcn_fdot2)
#define FDOT2(a, b, c) __builtin_amdgcn_fdot2((a), (b), (c), false)
#else
__device__ inline float FDOT2(h2 a, h2 b, float c) {
  return (float)a.x * (float)b.x + (float)a.y * (float)b.y + c;
}
#endif

#define MASK_X 0x00003C00u   // half2 (1,0)
#define MASK_Y 0x3C000000u   // half2 (0,1)

// acc[0..7] += convert of 8 halfs in v (via fdot2 with unit masks)
__device__ inline void acc8c(const uint4& v, float* acc) {
  const unsigned* w = (const unsigned*)&v;
#pragma unroll
  for (int k = 0; k < 4; k++) {
    h2 hv = h2bits(w[k]);
    acc[2 * k]     = FDOT2(hv, h2bits(MASK_X), acc[2 * k]);
    acc[2 * k + 1] = FDOT2(hv, h2bits(MASK_Y), acc[2 * k + 1]);
  }
}

// W conversion to fp16 B-frag layout (blocks 0-2) + workspace zeroing
// (block 3: chist, block 4: hsum/hmax/cntg).  Launched first.
__global__ __launch_bounds__(256) void k_wcvt(const float* __restrict__ W0,
                                              const float* __restrict__ W1,
                                              const float* __restrict__ W2,
                                              _Float16* __restrict__ Wf,
                                              int* __restrict__ chist,
                                              float* __restrict__ hz, int hzn) {
  if (blockIdx.x < 3) {
    const float* W = (blockIdx.x == 0) ? W0 : (blockIdx.x == 1) ? W1 : W2;
    _Float16* out = Wf + blockIdx.x * 4096;
    for (int i = threadIdx.x; i < 4096; i += 256) {
      int c = i >> 10, s = (i >> 9) & 1, l = (i >> 3) & 63, j = i & 7;
      int k = 32 * s + 8 * (l >> 4) + j;
      int ncol = 16 * c + (l & 15);
      out[i] = (_Float16)W[k * 64 + ncol];
    }
  } else if (blockIdx.x == 3) {
    chist[threadIdx.x] = 0;
  } else {
    for (int i = threadIdx.x; i < hzn; i += 256) hz[i] = 0.f;
  }
}

// coarse histogram of dst >> BKT_LOG
__global__ __launch_bounds__(256) void k_chist(const int* __restrict__ dst,
                                               int* __restrict__ chist, int E, int B) {
  __shared__ int h[256];
  h[threadIdx.x] = 0;
  __syncthreads();
  for (long e = (long)blockIdx.x * blockDim.x + threadIdx.x; e < E;
       e += (long)gridDim.x * blockDim.x)
    atomicAdd(&h[dst[e] >> BKT_LOG], 1);
  __syncthreads();
  if (threadIdx.x < B && h[threadIdx.x]) atomicAdd(&chist[threadIdx.x], h[threadIdx.x]);
}

// exclusive scan of chist[B] -> cbase[B+1]; cursor copy -> gcur
__global__ __launch_bounds__(256) void k_cscan(const int* __restrict__ chist,
                                               int* __restrict__ cbase,
                                               int* __restrict__ gcur, int E, int B) {
  __shared__ int s[256];
  int v = (threadIdx.x < B) ? chist[threadIdx.x] : 0;
  s[threadIdx.x] = v;
  __syncthreads();
  for (int d = 1; d < 256; d <<= 1) {
    int t = (threadIdx.x >= (unsigned)d) ? s[threadIdx.x - d] : 0;
    __syncthreads();
    s[threadIdx.x] += t;
    __syncthreads();
  }
  if (threadIdx.x < B) {
    int ex = s[threadIdx.x] - v;
    cbase[threadIdx.x] = ex;
    gcur[threadIdx.x] = ex;
  }
  if (threadIdx.x == B) cbase[B] = E;
}

// partition: scatter packed (local_dst<<17 | src) into coarse-bucket order.
// LDS-staged: src/dst read exactly once from HBM.
__global__ __launch_bounds__(256) void k_part(const int* __restrict__ src,
                                              const int* __restrict__ dst,
                                              int* __restrict__ gcur,
                                              int* __restrict__ ebuf, int E, int B) {
  __shared__ int sA[CHUNK];
  __shared__ int dA[CHUNK];
  __shared__ int h[256], base[256];
  int tid = threadIdx.x;
  long c0 = (long)blockIdx.x * CHUNK;
  int m = (int)min((long)CHUNK, (long)E - c0);
  h[tid] = 0;
  __syncthreads();
  for (int i = tid; i < m; i += 256) {
    int s = src[c0 + i];
    int d = dst[c0 + i];
    sA[i] = s;
    dA[i] = d;
    atomicAdd(&h[d >> BKT_LOG], 1);
  }
  __syncthreads();
  if (tid < B && h[tid]) base[tid] = atomicAdd(&gcur[tid], h[tid]);
  __syncthreads();
  h[tid] = 0;   // reuse as per-bucket cursor
  __syncthreads();
  for (int i = tid; i < m; i += 256) {
    int s = sA[i], d = dA[i];
    int k = d >> BKT_LOG;
    int p = base[k] + atomicAdd(&h[k], 1);
    ebuf[p] = ((d & (BKT - 1)) << 17) | s;
  }
}

// per-bucket: node histogram + scan in LDS -> off/dinv, then place csrc.
__global__ __launch_bounds__(512) void k_bplace(const int* __restrict__ ebuf,
                                                const int* __restrict__ cbase,
                                                int* __restrict__ off,
                                                int* __restrict__ csrc,
                                                float* __restrict__ dinv,
                                                int N, int E) {
  __shared__ int s[512];
  __shared__ int cur[512];
  int b = blockIdx.x, tid = threadIdx.x;
  int n0 = b << BKT_LOG;
  int nn = min(BKT, N - n0);
  int e0 = cbase[b], e1 = cbase[b + 1];
  s[tid] = 0;
  __syncthreads();
  for (int e = e0 + tid; e < e1; e += 512) atomicAdd(&s[ebuf[e] >> 17], 1);
  __syncthreads();
  int deg = s[tid];
  for (int d = 1; d < 512; d <<= 1) {
    int t = (tid >= d) ? s[tid - d] : 0;
    __syncthreads();
    s[tid] += t;
    __syncthreads();
  }
  int excl = s[tid] - deg;
  if (tid < nn) {
    off[n0 + tid] = e0 + excl;
    dinv[n0 + tid] = 1.0f / sqrtf((float)(1 + deg));
  }
  cur[tid] = excl;
  __syncthreads();
  for (int e = e0 + tid; e < e1; e += 512) {
    int p = ebuf[e];
    int pos = e0 + atomicAdd(&cur[p >> 17], 1);
    csrc[pos] = p & 0x1FFFF;
  }
  if (b == 0 && tid == 0) off[N] = E;
}

// ---------------------------------------------------------------------------
// MFMA matmul: xh[c][node][16] = fp16( (in[node] @ W) * dinv[node]*scale )
// EMB: in = fp32 emb rows gathered by tok; else fp16 y in slab-major layout.
// ---------------------------------------------------------------------------
template <bool EMB>
__global__ __launch_bounds__(256) void k_mfmamm(const _Float16* __restrict__ y,
                                                const int* __restrict__ tok,
                                                const float* __restrict__ emb,
                                                const _Float16* __restrict__ Wf,
                                                const float* __restrict__ dinv,
                                                float scale,
                                                _Float16* __restrict__ xh,
                                                int n, int npad) {
  __shared__ _Float16 lds[4 * 16 * 72];
  int w = threadIdx.x >> 6, l = threadIdx.x & 63;
  int m = l & 15, q = l >> 4;
  int rbase = blockIdx.x * 64 + w * 16;

  f16x8 a0, a1;
  if (EMB) {
    int node = min(rbase + m, n - 1);
    const float* er = emb + (size_t)tok[node] * 64;
    float4 v0 = *(const float4*)(er + q * 8);
    float4 v1 = *(const float4*)(er + q * 8 + 4);
    float4 v2 = *(const float4*)(er + 32 + q * 8);
    float4 v3 = *(const float4*)(er + 32 + q * 8 + 4);
    a0[0] = (_Float16)v0.x; a0[1] = (_Float16)v0.y; a0[2] = (_Float16)v0.z; a0[3] = (_Float16)v0.w;
    a0[4] = (_Float16)v1.x; a0[5] = (_Float16)v1.y; a0[6] = (_Float16)v1.z; a0[7] = (_Float16)v1.w;
    a1[0] = (_Float16)v2.x; a1[1] = (_Float16)v2.y; a1[2] = (_Float16)v2.z; a1[3] = (_Float16)v2.w;
    a1[4] = (_Float16)v3.x; a1[5] = (_Float16)v3.y; a1[6] = (_Float16)v3.z; a1[7] = (_Float16)v3.w;
  } else {
    int node = rbase + m;
    a0 = *(const f16x8*)(y + ((size_t)(q >> 1) * npad + node) * 16 + (q & 1) * 8);
    a1 = *(const f16x8*)(y + ((size_t)((q >> 1) + 2) * npad + node) * 16 + (q & 1) * 8);
  }
  float4 d4 = *(const float4*)(dinv + rbase + q * 4);

  const f16x8* wf = (const f16x8*)Wf + l;
  f32x4 acc[4];
#pragma unroll
  for (int c = 0; c < 4; c++) {
    f32x4 z = {0.f, 0.f, 0.f, 0.f};
    z = __builtin_amdgcn_mfma_f32_16x16x32_f16(a0, wf[(c * 2 + 0) * 64], z, 0, 0, 0);
    z = __builtin_amdgcn_mfma_f32_16x16x32_f16(a1, wf[(c * 2 + 1) * 64], z, 0, 0, 0);
    acc[c] = z;
  }

  const float ds[4] = {d4.x * scale, d4.y * scale, d4.z * scale, d4.w * scale};
  _Float16* ldw = lds + w * 16 * 72;
#pragma unroll
  for (int c = 0; c < 4; c++)
#pragma unroll
    for (int r = 0; r < 4; r++)
      ldw[(q * 4 + r) * 72 + c * 16 + m] = (_Float16)(acc[c][r] * ds[r]);
  __syncthreads();

  int row2 = l & 15, c2 = l >> 4;
  int node = rbase + row2;
  if (node < n) {
    const uint4* s4 = (const uint4*)(ldw + row2 * 72 + c2 * 16);
    uint4 v0 = s4[0], v1 = s4[1];
    uint4* dst = (uint4*)(xh + ((size_t)c2 * npad + node) * 16);
    dst[0] = v0;
    dst[1] = v1;
  }
}

// ---------------------------------------------------------------------------
// Aggregate, slab-parallel, XCD-affine, depth-2 gather pipeline.
// chunk c = blockIdx&3; wave = 4 nodes; lane = (n4:bits4-5, g:bits1-3, o:bit0)
// out (slab-major [c][npad][16]) = fp16 4096*relu(conv + bias)
// conv = (dinv[t]/256) * (xh_c[t] + sum_in xh_c[s]).
// ---------------------------------------------------------------------------
__global__ __launch_bounds__(256) void k_aggregate(const int* __restrict__ off,
                                                   const int* __restrict__ csrc,
                                                   const float* __restrict__ dinv,
                                                   const _Float16* __restrict__ xh,
                                                   const float* __restrict__ bias,
                                                   _Float16* __restrict__ outp,
                                                   int n, int npad) {
  int c = blockIdx.x & 3;
  int lane = threadIdx.x & 63;
  int n4 = lane >> 4, g = (lane >> 1) & 7, o = lane & 1;
  int t = (blockIdx.x >> 2) * 16 + (threadIdx.x >> 6) * 4 + n4;
  bool valid = t < n;
  int tc = valid ? t : n - 1;
  int e0 = off[tc], e1 = off[tc + 1];
  if (!valid) e1 = e0;
  const uint4* x4 = (const uint4*)xh + (size_t)c * npad * 2;   // 32B rows

  float acc[8];
#pragma unroll
  for (int k = 0; k < 8; k++) acc[k] = 0.f;
  if (g == 0) acc8c(x4[(size_t)tc * 2 + o], acc);   // self term

  // depth-2 software pipeline: edges iA and iA+8 gathered concurrently.
  int iA = e0 + g;
  bool aA = iA < e1, aB = iA + 8 < e1;
  int sA = aA ? csrc[iA] : 0;
  int sB = aB ? csrc[iA + 8] : 0;
  while (aA) {
    uint4 vA = x4[(size_t)sA * 2 + o];
    uint4 vB;
    if (aB) vB = x4[(size_t)sB * 2 + o];
    int iN = iA + 16;
    bool aN = iN < e1, aM = iN + 8 < e1;
    int sN = 0, sM = 0;
    if (aN) sN = csrc[iN];
    if (aM) sM = csrc[iN + 8];
    acc8c(vA, acc);
    if (aB) acc8c(vB, acc);
    iA = iN; aA = aN; sA = sN;
    aB = aM; sB = sM;
  }

  // reduce over g (lane bits 1-3)
#pragma unroll
  for (int mm = 2; mm <= 8; mm <<= 1) {
#pragma unroll
    for (int k = 0; k < 8; k++) acc[k] += __shfl_xor(acc[k], mm);
  }

  if (valid && g == 0) {
    float sc = dinv[t] * (1.0f / 256.0f);
    int f0 = c * 16 + o * 8;
    float4 bb0 = *(const float4*)(bias + f0);
    float4 bb1 = *(const float4*)(bias + f0 + 4);
    const float bs[8] = {bb0.x, bb0.y, bb0.z, bb0.w, bb1.x, bb1.y, bb1.z, bb1.w};
    _Float16 hh[8];
#pragma unroll
    for (int k = 0; k < 8; k++)
      hh[k] = (_Float16)(fmaxf(acc[k] * sc + bs[k], 0.f) * 4096.f);
    *(uint4*)(outp + ((size_t)c * npad + t) * 16 + o * 8) = *(const uint4*)hh;
  }
}

// batch is sorted: per-wave register segment reduction over slab-major fp16 y.
__global__ __launch_bounds__(256) void k_pool(const _Float16* __restrict__ x,
                                              const int* __restrict__ batch,
                                              float* __restrict__ hsum,
                                              float* __restrict__ hmax,
                                              int* __restrict__ cntg,
                                              int n, int npad) {
  int wid = (blockIdx.x * blockDim.x + threadIdx.x) >> 6;
  int lane = threadIdx.x & 63;
  int i0 = wid * 64;
  if (i0 >= n) return;
  int i1 = min(i0 + 64, n);
  size_t sb = (size_t)(lane >> 4) * npad * 16 + (lane & 15);
  int batch_l = (i0 + lane < n) ? batch[i0 + lane] : 0;
  float gsum = 0.f, gmax = 0.f;
  int cur = __shfl(batch_l, 0);
  int c = 0;
  for (int i = i0; i < i1; i++) {
    int g = __shfl(batch_l, i - i0);
    if (g != cur) {
      atomicAdd(&hsum[cur * 64 + lane], gsum);
      atomicMax((int*)&hmax[cur * 64 + lane], __float_as_int(gmax));
      if (lane == 0) atomicAdd(&cntg[cur], c);
      gsum = 0.f; gmax = 0.f; c = 0; cur = g;
    }
    float v = (float)x[sb + (size_t)i * 16];   // relu+bias folded, x4096
    gsum += v;
    gmax = fmaxf(gmax, v);
    c++;
  }
  atomicAdd(&hsum[cur * 64 + lane], gsum);
  atomicMax((int*)&hmax[cur * 64 + lane], __float_as_int(gmax));
  if (lane == 0) atomicAdd(&cntg[cur], c);
}

// one block (64 threads) per graph: logits = relu(h@Wc1+bc1)@Wc2+bc2
// hsum/hmax carry the 4096x scale; undone here.
__global__ __launch_bounds__(64) void k_cls(const float* __restrict__ hsum,
                                            const float* __restrict__ hmax,
                                            const int* __restrict__ cnt,
                                            const float* __restrict__ Wc1,
                                            const float* __restrict__ bc1,
                                            const float* __restrict__ Wc2,
                                            const float* __restrict__ bc2,
                                            float* __restrict__ out) {
  __shared__ float h[128];
  __shared__ float hid[64];
  int g = blockIdx.x, j = threadIdx.x;
  int c = cnt[g];
  float cf = (float)(c > 0 ? c : 1);
  h[j] = hsum[g * 64 + j] / cf * (1.0f / 4096.0f);
  h[64 + j] = hmax[g * 64 + j] * (1.0f / 4096.0f);
  __syncthreads();
  float acc = bc1[j];
  for (int k = 0; k < 128; k++) acc += h[k] * Wc1[k * 64 + j];
  hid[j] = fmaxf(acc, 0.f);
  __syncthreads();
  if (j < 2) {
    float a = bc2[j];
    for (int k = 0; k < 64; k++) a += hid[k] * Wc2[k * 2 + j];
    out[g * 2 + j] = a;
  }
}

extern "C" void kernel_launch(void* const* d_in, const int* in_sizes, int n_in,
                              void* d_out, int out_size, void* d_ws, size_t ws_size,
                              hipStream_t stream) {
  const int N = in_sizes[0];
  const int E = in_sizes[1] / 2;
  const int G = out_size / 2;
  const int B = (N + BKT - 1) >> BKT_LOG;
  const int Npad = (N + 63) & ~63;

  const int* tok   = (const int*)d_in[0];
  const int* ei    = (const int*)d_in[1];
  const int* batch = (const int*)d_in[2];
  const float* emb = (const float*)d_in[3];
  const float* W0 = (const float*)d_in[4];  const float* b0 = (const float*)d_in[5];
  const float* W1 = (const float*)d_in[6];  const float* b1 = (const float*)d_in[7];
  const float* W2 = (const float*)d_in[8];  const float* b2 = (const float*)d_in[9];
  const float* Wc1 = (const float*)d_in[10]; const float* bc1 = (const float*)d_in[11];
  const float* Wc2 = (const float*)d_in[12]; const float* bc2 = (const float*)d_in[13];
  const int* srcp = ei;
  const int* dstp = ei + E;

  // ---- workspace carve-up (4-byte units) ----
  int* off    = (int*)d_ws;                      // N+2
  int* csrc   = off + N + 2;                     // E
  float* dinv = (float*)(csrc + E);              // Npad
  int* chist  = (int*)(dinv + Npad);             // 256
  int* cbase  = chist + 256;                     // 256 (B+1 used)
  int* gcur   = cbase + 256;                     // 256
  _Float16* Wf = (_Float16*)(gcur + 256);        // 3*4096 halfs
  _Float16* xh = Wf + 3 * 4096;                  // 4 slabs x Npad x 16 halfs
  _Float16* y  = xh + (size_t)Npad * 64;         // 4 slabs x Npad x 16 halfs
  int* ebuf   = (int*)(y + (size_t)Npad * 64);   // E ints (dead after bplace)
  float* hsum = (float*)(ebuf + E);              // G*64
  float* hmax = hsum + (size_t)G * 64;           // G*64
  int*   cntg = (int*)(hmax + (size_t)G * 64);   // G

  auto cdiv = [](long a, long b) { return (int)((a + b - 1) / b); };
  const int aggBlocks = 4 * cdiv(N, 16);   // blockIdx&3 = slab -> XCD affine

  // ---- weight conversion + workspace zeroing ----
  k_wcvt<<<5, 256, 0, stream>>>(W0, W1, W2, Wf, chist, hsum, G * 129);

  // ---- CSR build ----
  k_chist<<<cdiv(E, CHUNK), 256, 0, stream>>>(dstp, chist, E, B);
  k_cscan<<<1, 256, 0, stream>>>(chist, cbase, gcur, E, B);
  k_part<<<cdiv(E, CHUNK), 256, 0, stream>>>(srcp, dstp, gcur, ebuf, E, B);
  k_bplace<<<B, 512, 0, stream>>>(ebuf, cbase, off, csrc, dinv, N, E);

  // ---- 3 GCN layers ----
  k_mfmamm<true><<<cdiv(N, 64), 256, 0, stream>>>(nullptr, tok, emb, Wf, dinv, 256.f, xh, N, Npad);
  k_aggregate<<<aggBlocks, 256, 0, stream>>>(off, csrc, dinv, xh, b0, y, N, Npad);

  k_mfmamm<false><<<cdiv(N, 64), 256, 0, stream>>>(y, nullptr, nullptr, Wf + 4096, dinv, 1.f / 16.f, xh, N, Npad);
  k_aggregate<<<aggBlocks, 256, 0, stream>>>(off, csrc, dinv, xh, b1, y, N, Npad);

  k_mfmamm<false><<<cdiv(N, 64), 256, 0, stream>>>(y, nullptr, nullptr, Wf + 8192, dinv, 1.f / 16.f, xh, N, Npad);
  k_aggregate<<<aggBlocks, 256, 0, stream>>>(off, csrc, dinv, xh, b2, y, N, Npad);

  // ---- pooling ----
  k_pool<<<cdiv(N, 256), 256, 0, stream>>>(y, batch, hsum, hmax, cntg, N, Npad);

  // ---- classifier head ----
  k_cls<<<G, 64, 0, stream>>>(hsum, hmax, cntg, Wc1, bc1, Wc2, bc2, (float*)d_out);
}

// Round 16
// 332.283 us; speedup vs baseline: 1.1503x; 1.1016x over previous
//
#include <hip/hip_runtime.h>
#include <hip/hip_fp16.h>
#include <math.h>

// ---------------------------------------------------------------------------
// DevignLite: 3-layer GCN + mean/max pool + MLP head.  N=100000, E=1.6M,
// D=64, G=256.
// Round 16: padded-bucket CSR build.  k_chist + k_cscan DELETED: each coarse
// bucket (512 nodes) owns a fixed-stride region of S slots in ebuf/csrc
// (S = 1.5x mean + 256 = +45 sigma for Binomial occupancy); k_part claims
// slices from zero-init cursors; k_bplace reads final counts from the same
// cursors; per-node off[]/end[] replace the global prefix (aggregate already
// loads 2 values per node).  Store clamp: overflow drops edges, never
// corrupts.  -2 dispatches, -6.4MB pass.
// Ledger: r12=372; r13 ticket fusion REVERTED (+16); r14 pool fusion
// REVERTED (+24 on agg3); r15=366 clean.
// ---------------------------------------------------------------------------

#define BKT_LOG 9
#define BKT (1 << BKT_LOG)
#define CHUNK 4096

typedef _Float16 h2 __attribute__((ext_vector_type(2)));
typedef _Float16 f16x8 __attribute__((ext_vector_type(8)));
typedef float f32x4 __attribute__((ext_vector_type(4)));

union HU { unsigned u; h2 h; };
__device__ inline h2 h2bits(unsigned u) { HU x; x.u = u; return x.h; }

#if __has_builtin(__builtin_amdgcn_fdot2)
#define FDOT2(a, b, c) __builtin_amdgcn_fdot2((a), (b), (c), false)
#else
__device__ inline float FDOT2(h2 a, h2 b, float c) {
  return (float)a.x * (float)b.x + (float)a.y * (float)b.y + c;
}
#endif

#define MASK_X 0x00003C00u   // half2 (1,0)
#define MASK_Y 0x3C000000u   // half2 (0,1)

// acc[0..7] += convert of 8 halfs in v (via fdot2 with unit masks)
__device__ inline void acc8c(const uint4& v, float* acc) {
  const unsigned* w = (const unsigned*)&v;
#pragma unroll
  for (int k = 0; k < 4; k++) {
    h2 hv = h2bits(w[k]);
    acc[2 * k]     = FDOT2(hv, h2bits(MASK_X), acc[2 * k]);
    acc[2 * k + 1] = FDOT2(hv, h2bits(MASK_Y), acc[2 * k + 1]);
  }
}

// W conversion to fp16 B-frag layout (blocks 0-2) + workspace zeroing
// (block 3: bucket cursors, block 4: hsum/hmax/cntg).  Launched first.
__global__ __launch_bounds__(256) void k_wcvt(const float* __restrict__ W0,
                                              const float* __restrict__ W1,
                                              const float* __restrict__ W2,
                                              _Float16* __restrict__ Wf,
                                              int* __restrict__ gcur,
                                              float* __restrict__ hz, int hzn) {
  if (blockIdx.x < 3) {
    const float* W = (blockIdx.x == 0) ? W0 : (blockIdx.x == 1) ? W1 : W2;
    _Float16* out = Wf + blockIdx.x * 4096;
    for (int i = threadIdx.x; i < 4096; i += 256) {
      int c = i >> 10, s = (i >> 9) & 1, l = (i >> 3) & 63, j = i & 7;
      int k = 32 * s + 8 * (l >> 4) + j;
      int ncol = 16 * c + (l & 15);
      out[i] = (_Float16)W[k * 64 + ncol];
    }
  } else if (blockIdx.x == 3) {
    gcur[threadIdx.x] = 0;
  } else {
    for (int i = threadIdx.x; i < hzn; i += 256) hz[i] = 0.f;
  }
}

// partition: scatter packed (local_dst<<17 | src) into per-bucket padded
// regions (bucket b owns ebuf[b*S .. b*S+S)).  Cursors zero-initialized;
// block claims a contiguous slice per bucket -> single writer per line.
// LDS-staged: src/dst read exactly once from HBM.
__global__ __launch_bounds__(256) void k_part(const int* __restrict__ src,
                                              const int* __restrict__ dst,
                                              int* __restrict__ gcur,
                                              int* __restrict__ ebuf,
                                              int E, int S) {
  __shared__ int sA[CHUNK];
  __shared__ int dA[CHUNK];
  __shared__ int h[256], base[256];
  int tid = threadIdx.x;
  long c0 = (long)blockIdx.x * CHUNK;
  int m = (int)min((long)CHUNK, (long)E - c0);
  h[tid] = 0;
  __syncthreads();
  for (int i = tid; i < m; i += 256) {
    int s = src[c0 + i];
    int d = dst[c0 + i];
    sA[i] = s;
    dA[i] = d;
    atomicAdd(&h[d >> BKT_LOG], 1);
  }
  __syncthreads();
  if (h[tid]) base[tid] = atomicAdd(&gcur[tid], h[tid]);
  __syncthreads();
  h[tid] = 0;   // reuse as per-bucket cursor
  __syncthreads();
  for (int i = tid; i < m; i += 256) {
    int s = sA[i], d = dA[i];
    int k = d >> BKT_LOG;
    int p = base[k] + atomicAdd(&h[k], 1);
    if (p < S)   // overflow guard (S = mean+45sigma: never taken in practice)
      ebuf[k * S + p] = ((d & (BKT - 1)) << 17) | s;
  }
}

// per-bucket: node histogram + scan in LDS -> off/end/dinv, then place csrc
// within the bucket's padded region (single-writer).
__global__ __launch_bounds__(512) void k_bplace(const int* __restrict__ ebuf,
                                                const int* __restrict__ gcur,
                                                int* __restrict__ off,
                                                int* __restrict__ eend,
                                                int* __restrict__ csrc,
                                                float* __restrict__ dinv,
                                                int N, int S) {
  __shared__ int s[512];
  __shared__ int cur[512];
  int b = blockIdx.x, tid = threadIdx.x;
  int n0 = b << BKT_LOG;
  int nn = min(BKT, N - n0);
  int e0 = b * S;
  int cnt = min(gcur[b], S);
  s[tid] = 0;
  __syncthreads();
  for (int e = tid; e < cnt; e += 512) atomicAdd(&s[ebuf[e0 + e] >> 17], 1);
  __syncthreads();
  int deg = s[tid];
  for (int d = 1; d < 512; d <<= 1) {
    int t = (tid >= d) ? s[tid - d] : 0;
    __syncthreads();
    s[tid] += t;
    __syncthreads();
  }
  int excl = s[tid] - deg;
  if (tid < nn) {
    off[n0 + tid] = e0 + excl;
    eend[n0 + tid] = e0 + excl + deg;
    dinv[n0 + tid] = 1.0f / sqrtf((float)(1 + deg));
  }
  cur[tid] = excl;
  __syncthreads();
  for (int e = tid; e < cnt; e += 512) {
    int p = ebuf[e0 + e];
    int pos = e0 + atomicAdd(&cur[p >> 17], 1);
    csrc[pos] = p & 0x1FFFF;
  }
}

// ---------------------------------------------------------------------------
// MFMA matmul: xh[c][node][16] = fp16( (in[node] @ W) * dinv[node]*scale )
// EMB: in = fp32 emb rows gathered by tok; else fp16 y in slab-major layout.
// ---------------------------------------------------------------------------
template <bool EMB>
__global__ __launch_bounds__(256) void k_mfmamm(const _Float16* __restrict__ y,
                                                const int* __restrict__ tok,
                                                const float* __restrict__ emb,
                                                const _Float16* __restrict__ Wf,
                                                const float* __restrict__ dinv,
                                                float scale,
                                                _Float16* __restrict__ xh,
                                                int n, int npad) {
  __shared__ _Float16 lds[4 * 16 * 72];
  int w = threadIdx.x >> 6, l = threadIdx.x & 63;
  int m = l & 15, q = l >> 4;
  int rbase = blockIdx.x * 64 + w * 16;

  f16x8 a0, a1;
  if (EMB) {
    int node = min(rbase + m, n - 1);
    const float* er = emb + (size_t)tok[node] * 64;
    float4 v0 = *(const float4*)(er + q * 8);
    float4 v1 = *(const float4*)(er + q * 8 + 4);
    float4 v2 = *(const float4*)(er + 32 + q * 8);
    float4 v3 = *(const float4*)(er + 32 + q * 8 + 4);
    a0[0] = (_Float16)v0.x; a0[1] = (_Float16)v0.y; a0[2] = (_Float16)v0.z; a0[3] = (_Float16)v0.w;
    a0[4] = (_Float16)v1.x; a0[5] = (_Float16)v1.y; a0[6] = (_Float16)v1.z; a0[7] = (_Float16)v1.w;
    a1[0] = (_Float16)v2.x; a1[1] = (_Float16)v2.y; a1[2] = (_Float16)v2.z; a1[3] = (_Float16)v2.w;
    a1[4] = (_Float16)v3.x; a1[5] = (_Float16)v3.y; a1[6] = (_Float16)v3.z; a1[7] = (_Float16)v3.w;
  } else {
    int node = rbase + m;
    a0 = *(const f16x8*)(y + ((size_t)(q >> 1) * npad + node) * 16 + (q & 1) * 8);
    a1 = *(const f16x8*)(y + ((size_t)((q >> 1) + 2) * npad + node) * 16 + (q & 1) * 8);
  }
  float4 d4 = *(const float4*)(dinv + rbase + q * 4);

  const f16x8* wf = (const f16x8*)Wf + l;
  f32x4 acc[4];
#pragma unroll
  for (int c = 0; c < 4; c++) {
    f32x4 z = {0.f, 0.f, 0.f, 0.f};
    z = __builtin_amdgcn_mfma_f32_16x16x32_f16(a0, wf[(c * 2 + 0) * 64], z, 0, 0, 0);
    z = __builtin_amdgcn_mfma_f32_16x16x32_f16(a1, wf[(c * 2 + 1) * 64], z, 0, 0, 0);
    acc[c] = z;
  }

  const float ds[4] = {d4.x * scale, d4.y * scale, d4.z * scale, d4.w * scale};
  _Float16* ldw = lds + w * 16 * 72;
#pragma unroll
  for (int c = 0; c < 4; c++)
#pragma unroll
    for (int r = 0; r < 4; r++)
      ldw[(q * 4 + r) * 72 + c * 16 + m] = (_Float16)(acc[c][r] * ds[r]);
  __syncthreads();

  int row2 = l & 15, c2 = l >> 4;
  int node = rbase + row2;
  if (node < n) {
    const uint4* s4 = (const uint4*)(ldw + row2 * 72 + c2 * 16);
    uint4 v0 = s4[0], v1 = s4[1];
    uint4* dst = (uint4*)(xh + ((size_t)c2 * npad + node) * 16);
    dst[0] = v0;
    dst[1] = v1;
  }
}

// ---------------------------------------------------------------------------
// Aggregate, slab-parallel, XCD-affine, depth-2 gather pipeline.
// chunk c = blockIdx&3; wave = 4 nodes; lane = (n4:bits4-5, g:bits1-3, o:bit0)
// out (slab-major [c][npad][16]) = fp16 4096*relu(conv + bias)
// conv = (dinv[t]/256) * (xh_c[t] + sum_in xh_c[s]).
// ---------------------------------------------------------------------------
__global__ __launch_bounds__(256) void k_aggregate(const int* __restrict__ off,
                                                   const int* __restrict__ eend,
                                                   const int* __restrict__ csrc,
                                                   const float* __restrict__ dinv,
                                                   const _Float16* __restrict__ xh,
                                                   const float* __restrict__ bias,
                                                   _Float16* __restrict__ outp,
                                                   int n, int npad) {
  int c = blockIdx.x & 3;
  int lane = threadIdx.x & 63;
  int n4 = lane >> 4, g = (lane >> 1) & 7, o = lane & 1;
  int t = (blockIdx.x >> 2) * 16 + (threadIdx.x >> 6) * 4 + n4;
  bool valid = t < n;
  int tc = valid ? t : n - 1;
  int e0 = off[tc], e1 = eend[tc];
  if (!valid) e1 = e0;
  const uint4* x4 = (const uint4*)xh + (size_t)c * npad * 2;   // 32B rows

  float acc[8];
#pragma unroll
  for (int k = 0; k < 8; k++) acc[k] = 0.f;
  if (g == 0) acc8c(x4[(size_t)tc * 2 + o], acc);   // self term

  // depth-2 software pipeline: edges iA and iA+8 gathered concurrently.
  int iA = e0 + g;
  bool aA = iA < e1, aB = iA + 8 < e1;
  int sA = aA ? csrc[iA] : 0;
  int sB = aB ? csrc[iA + 8] : 0;
  while (aA) {
    uint4 vA = x4[(size_t)sA * 2 + o];
    uint4 vB;
    if (aB) vB = x4[(size_t)sB * 2 + o];
    int iN = iA + 16;
    bool aN = iN < e1, aM = iN + 8 < e1;
    int sN = 0, sM = 0;
    if (aN) sN = csrc[iN];
    if (aM) sM = csrc[iN + 8];
    acc8c(vA, acc);
    if (aB) acc8c(vB, acc);
    iA = iN; aA = aN; sA = sN;
    aB = aM; sB = sM;
  }

  // reduce over g (lane bits 1-3)
#pragma unroll
  for (int mm = 2; mm <= 8; mm <<= 1) {
#pragma unroll
    for (int k = 0; k < 8; k++) acc[k] += __shfl_xor(acc[k], mm);
  }

  if (valid && g == 0) {
    float sc = dinv[t] * (1.0f / 256.0f);
    int f0 = c * 16 + o * 8;
    float4 bb0 = *(const float4*)(bias + f0);
    float4 bb1 = *(const float4*)(bias + f0 + 4);
    const float bs[8] = {bb0.x, bb0.y, bb0.z, bb0.w, bb1.x, bb1.y, bb1.z, bb1.w};
    _Float16 hh[8];
#pragma unroll
    for (int k = 0; k < 8; k++)
      hh[k] = (_Float16)(fmaxf(acc[k] * sc + bs[k], 0.f) * 4096.f);
    *(uint4*)(outp + ((size_t)c * npad + t) * 16 + o * 8) = *(const uint4*)hh;
  }
}

// batch is sorted: per-wave register segment reduction over slab-major fp16 y.
__global__ __launch_bounds__(256) void k_pool(const _Float16* __restrict__ x,
                                              const int* __restrict__ batch,
                                              float* __restrict__ hsum,
                                              float* __restrict__ hmax,
                                              int* __restrict__ cntg,
                                              int n, int npad) {
  int wid = (blockIdx.x * blockDim.x + threadIdx.x) >> 6;
  int lane = threadIdx.x & 63;
  int i0 = wid * 64;
  if (i0 >= n) return;
  int i1 = min(i0 + 64, n);
  size_t sb = (size_t)(lane >> 4) * npad * 16 + (lane & 15);
  int batch_l = (i0 + lane < n) ? batch[i0 + lane] : 0;
  float gsum = 0.f, gmax = 0.f;
  int cur = __shfl(batch_l, 0);
  int c = 0;
  for (int i = i0; i < i1; i++) {
    int g = __shfl(batch_l, i - i0);
    if (g != cur) {
      atomicAdd(&hsum[cur * 64 + lane], gsum);
      atomicMax((int*)&hmax[cur * 64 + lane], __float_as_int(gmax));
      if (lane == 0) atomicAdd(&cntg[cur], c);
      gsum = 0.f; gmax = 0.f; c = 0; cur = g;
    }
    float v = (float)x[sb + (size_t)i * 16];   // relu+bias folded, x4096
    gsum += v;
    gmax = fmaxf(gmax, v);
    c++;
  }
  atomicAdd(&hsum[cur * 64 + lane], gsum);
  atomicMax((int*)&hmax[cur * 64 + lane], __float_as_int(gmax));
  if (lane == 0) atomicAdd(&cntg[cur], c);
}

// one block (64 threads) per graph: logits = relu(h@Wc1+bc1)@Wc2+bc2
// hsum/hmax carry the 4096x scale; undone here.
__global__ __launch_bounds__(64) void k_cls(const float* __restrict__ hsum,
                                            const float* __restrict__ hmax,
                                            const int* __restrict__ cnt,
                                            const float* __restrict__ Wc1,
                                            const float* __restrict__ bc1,
                                            const float* __restrict__ Wc2,
                                            const float* __restrict__ bc2,
                                            float* __restrict__ out) {
  __shared__ float h[128];
  __shared__ float hid[64];
  int g = blockIdx.x, j = threadIdx.x;
  int c = cnt[g];
  float cf = (float)(c > 0 ? c : 1);
  h[j] = hsum[g * 64 + j] / cf * (1.0f / 4096.0f);
  h[64 + j] = hmax[g * 64 + j] * (1.0f / 4096.0f);
  __syncthreads();
  float acc = bc1[j];
  for (int k = 0; k < 128; k++) acc += h[k] * Wc1[k * 64 + j];
  hid[j] = fmaxf(acc, 0.f);
  __syncthreads();
  if (j < 2) {
    float a = bc2[j];
    for (int k = 0; k < 64; k++) a += hid[k] * Wc2[k * 2 + j];
    out[g * 2 + j] = a;
  }
}

extern "C" void kernel_launch(void* const* d_in, const int* in_sizes, int n_in,
                              void* d_out, int out_size, void* d_ws, size_t ws_size,
                              hipStream_t stream) {
  const int N = in_sizes[0];
  const int E = in_sizes[1] / 2;
  const int G = out_size / 2;
  const int B = (N + BKT - 1) >> BKT_LOG;
  const int Npad = (N + 63) & ~63;
  // padded bucket stride: 1.5x mean occupancy + 256, rounded to 4
  const int S = ((((E + B - 1) / B) * 3 / 2 + 256) + 3) & ~3;

  const int* tok   = (const int*)d_in[0];
  const int* ei    = (const int*)d_in[1];
  const int* batch = (const int*)d_in[2];
  const float* emb = (const float*)d_in[3];
  const float* W0 = (const float*)d_in[4];  const float* b0 = (const float*)d_in[5];
  const float* W1 = (const float*)d_in[6];  const float* b1 = (const float*)d_in[7];
  const float* W2 = (const float*)d_in[8];  const float* b2 = (const float*)d_in[9];
  const float* Wc1 = (const float*)d_in[10]; const float* bc1 = (const float*)d_in[11];
  const float* Wc2 = (const float*)d_in[12]; const float* bc2 = (const float*)d_in[13];
  const int* srcp = ei;
  const int* dstp = ei + E;

  // ---- workspace carve-up (4-byte units) ----
  int* off    = (int*)d_ws;                      // N
  int* eend   = off + N;                         // N
  float* dinv = (float*)(eend + N);              // Npad
  int* gcur   = (int*)(dinv + Npad);             // 256
  _Float16* Wf = (_Float16*)(gcur + 256);        // 3*4096 halfs (24 KB)
  int* csrc   = (int*)(Wf + 3 * 4096);           // B*S (padded, ~9.6 MB)
  _Float16* xh = (_Float16*)(csrc + (size_t)B * S);  // 4 slabs x Npad x 16
  _Float16* y  = xh + (size_t)Npad * 64;         // 4 slabs x Npad x 16
  int* ebuf   = (int*)y;                         // B*S ints, aliases y (dead
                                                 // before first aggregate)
  float* hsum = (float*)(y + (size_t)Npad * 64); // G*64
  float* hmax = hsum + (size_t)G * 64;           // G*64
  int*   cntg = (int*)(hmax + (size_t)G * 64);   // G

  auto cdiv = [](long a, long b) { return (int)((a + b - 1) / b); };
  const int aggBlocks = 4 * cdiv(N, 16);   // blockIdx&3 = slab -> XCD affine

  // ---- weight conversion + workspace zeroing ----
  k_wcvt<<<5, 256, 0, stream>>>(W0, W1, W2, Wf, gcur, hsum, G * 129);

  // ---- CSR build (padded buckets; no histogram/scan kernels) ----
  k_part<<<cdiv(E, CHUNK), 256, 0, stream>>>(srcp, dstp, gcur, ebuf, E, S);
  k_bplace<<<B, 512, 0, stream>>>(ebuf, gcur, off, eend, csrc, dinv, N, S);

  // ---- 3 GCN layers ----
  k_mfmamm<true><<<cdiv(N, 64), 256, 0, stream>>>(nullptr, tok, emb, Wf, dinv, 256.f, xh, N, Npad);
  k_aggregate<<<aggBlocks, 256, 0, stream>>>(off, eend, csrc, dinv, xh, b0, y, N, Npad);

  k_mfmamm<false><<<cdiv(N, 64), 256, 0, stream>>>(y, nullptr, nullptr, Wf + 4096, dinv, 1.f / 16.f, xh, N, Npad);
  k_aggregate<<<aggBlocks, 256, 0, stream>>>(off, eend, csrc, dinv, xh, b1, y, N, Npad);

  k_mfmamm<false><<<cdiv(N, 64), 256, 0, stream>>>(y, nullptr, nullptr, Wf + 8192, dinv, 1.f / 16.f, xh, N, Npad);
  k_aggregate<<<aggBlocks, 256, 0, stream>>>(off, eend, csrc, dinv, xh, b2, y, N, Npad);

  // ---- pooling ----
  k_pool<<<cdiv(N, 256), 256, 0, stream>>>(y, batch, hsum, hmax, cntg, N, Npad);

  // ---- classifier head ----
  k_cls<<<G, 64, 0, stream>>>(hsum, hmax, cntg, Wc1, bc1, Wc2, bc2, (float*)d_out);
}